// Round 14
// baseline (198.181 us; speedup 1.0000x reference)
//
#include <hip/hip_runtime.h>
#include <hip/hip_bf16.h>

typedef short bf16x8 __attribute__((ext_vector_type(8)));
typedef float f32x4 __attribute__((ext_vector_type(4)));

#define EMB 1024
#define NH 16
#define SEQ 2048
#define BATCH 4
#define MROWS (BATCH * SEQ)

static __device__ inline unsigned short f2bf(float f) {
  unsigned u = __float_as_uint(f);
  u += 0x7fffu + ((u >> 16) & 1u);
  return (unsigned short)(u >> 16);
}

static __device__ inline unsigned cvtpk(float lo, float hi) {
  unsigned r;
  asm("v_cvt_pk_bf16_f32 %0, %1, %2" : "=v"(r) : "v"(lo), "v"(hi));
  return r;
}

static __device__ inline void gload16(const void* g, void* l) {
  __builtin_amdgcn_global_load_lds(
      (const __attribute__((address_space(1))) unsigned int*)g,
      (__attribute__((address_space(3))) unsigned int*)l, 16, 0, 0);
}

// ---------------- weight transpose + cast: W[k][n] f32 -> WT[n][k] bf16 ----------------
// z==0 (Wq) additionally folds in 0.125*log2(e) so attention logits are in exp2 domain.
__global__ __launch_bounds__(256) void wtrans_kernel(
    const float* w0, const float* w1, const float* w2, const float* w3,
    unsigned short* o0, unsigned short* o1, unsigned short* o2, unsigned short* o3) {
  __shared__ float t[32][33];
  int z = blockIdx.z;
  const float* W = z == 0 ? w0 : z == 1 ? w1 : z == 2 ? w2 : w3;
  unsigned short* O = z == 0 ? o0 : z == 1 ? o1 : z == 2 ? o2 : o3;
  float sc = (z == 0) ? 0.18033688011112042f : 1.0f;
  int bx = blockIdx.x * 32;  // k block
  int by = blockIdx.y * 32;  // n block
  int tx = threadIdx.x, ty = threadIdx.y;  // (32,8)
#pragma unroll
  for (int j = 0; j < 4; ++j)
    t[ty + j * 8][tx] = W[(size_t)(bx + ty + j * 8) * EMB + by + tx];
  __syncthreads();
#pragma unroll
  for (int j = 0; j < 4; ++j)
    O[(size_t)(by + ty + j * 8) * EMB + bx + tx] = f2bf(t[tx][ty + j * 8] * sc);
}

// ---------------- GEMM: C[M=8192][N=1024] = A[M][K=1024] * BT[N][K]^T ----------------
// IN_F32: 1 = A is f32 (reg-prefetched next tile, cvtpk on write), 0 = A bf16 (gload16)
// OUT_MODE: 0 = bf16 normal [m][n], 1 = bf16 V-transposed [b][h][dv][l], 2 = f32 [m][n]
template <int IN_F32, int OUT_MODE>
__global__ __launch_bounds__(256) void gemm_kernel(const void* Ap, const unsigned short* Bt, void* Cp) {
  __shared__ __align__(16) unsigned short As[128 * 64];  // XOR-swizzled cols
  __shared__ __align__(16) unsigned short Bs[128 * 64];
  const int K = EMB;
  int tid = threadIdx.x;
  int lane = tid & 63, wave = tid >> 6;
  int q = lane & 15, g = lane >> 4;
  int qx7 = q & 7;
  int wm = (wave >> 1) * 64, wn = (wave & 1) * 64;
  int lin = blockIdx.x + (blockIdx.y << 3);
  int idx = (lin & 7) * 64 + (lin >> 3);
  int tm = (idx >> 3) * 128, tn = (idx & 7) * 128;
  f32x4 acc[4][4] = {};
  int arow = tid >> 3, acb = tid & 7;  // this thread's A-stage row/chunk (row += 32/iter)
  const float* Af = (const float*)Ap;
  float4 pf0a, pf0b, pf1a, pf1b, pf2a, pf2b, pf3a, pf3b;  // prefetched A f32 (next tile)
  if (IN_F32) {
    // prologue prefetch for kt=0
    const float4* s0 = (const float4*)(Af + (size_t)(tm + arow) * K + acb * 8);
    pf0a = s0[0]; pf0b = s0[1];
    const float4* s1 = (const float4*)(Af + (size_t)(tm + arow + 32) * K + acb * 8);
    pf1a = s1[0]; pf1b = s1[1];
    const float4* s2 = (const float4*)(Af + (size_t)(tm + arow + 64) * K + acb * 8);
    pf2a = s2[0]; pf2b = s2[1];
    const float4* s3 = (const float4*)(Af + (size_t)(tm + arow + 96) * K + acb * 8);
    pf3a = s3[0]; pf3b = s3[1];
  }
  for (int kt = 0; kt < K; kt += 64) {
    if (IN_F32) {
      // write prefetched A (f32 regs -> bf16 LDS)
      uint4 w;
      w.x = cvtpk(pf0a.x, pf0a.y); w.y = cvtpk(pf0a.z, pf0a.w);
      w.z = cvtpk(pf0b.x, pf0b.y); w.w = cvtpk(pf0b.z, pf0b.w);
      *(uint4*)&As[arow * 64 + 8 * (acb ^ (arow & 7))] = w;
      w.x = cvtpk(pf1a.x, pf1a.y); w.y = cvtpk(pf1a.z, pf1a.w);
      w.z = cvtpk(pf1b.x, pf1b.y); w.w = cvtpk(pf1b.z, pf1b.w);
      *(uint4*)&As[(arow + 32) * 64 + 8 * (acb ^ (arow & 7))] = w;
      w.x = cvtpk(pf2a.x, pf2a.y); w.y = cvtpk(pf2a.z, pf2a.w);
      w.z = cvtpk(pf2b.x, pf2b.y); w.w = cvtpk(pf2b.z, pf2b.w);
      *(uint4*)&As[(arow + 64) * 64 + 8 * (acb ^ (arow & 7))] = w;
      w.x = cvtpk(pf3a.x, pf3a.y); w.y = cvtpk(pf3a.z, pf3a.w);
      w.z = cvtpk(pf3b.x, pf3b.y); w.w = cvtpk(pf3b.z, pf3b.w);
      *(uint4*)&As[(arow + 96) * 64 + 8 * (acb ^ (arow & 7))] = w;
    } else {
      const unsigned short* A = (const unsigned short*)Ap;
#pragma unroll
      for (int it = 0; it < 4; ++it) {
        int gid = tid + it * 256;
        int row = gid >> 3, cb = gid & 7;
        gload16(A + (size_t)(tm + row) * K + kt + 8 * (cb ^ (row & 7)), &As[gid * 8]);
      }
    }
#pragma unroll
    for (int it = 0; it < 4; ++it) {
      int gid = tid + it * 256;
      int row = gid >> 3, cb = gid & 7;
      gload16(Bt + (size_t)(tn + row) * K + kt + 8 * (cb ^ (row & 7)), &Bs[gid * 8]);
    }
    __syncthreads();
    if (IN_F32 && kt + 64 < K) {
      // issue next tile's A loads now; latency hides under the MFMA compute below
      int ko = kt + 64;
      const float4* s0 = (const float4*)(Af + (size_t)(tm + arow) * K + ko + acb * 8);
      pf0a = s0[0]; pf0b = s0[1];
      const float4* s1 = (const float4*)(Af + (size_t)(tm + arow + 32) * K + ko + acb * 8);
      pf1a = s1[0]; pf1b = s1[1];
      const float4* s2 = (const float4*)(Af + (size_t)(tm + arow + 64) * K + ko + acb * 8);
      pf2a = s2[0]; pf2b = s2[1];
      const float4* s3 = (const float4*)(Af + (size_t)(tm + arow + 96) * K + ko + acb * 8);
      pf3a = s3[0]; pf3b = s3[1];
    }
#pragma unroll
    for (int s = 0; s < 2; ++s) {
      bf16x8 af[4], bfr[4];
#pragma unroll
      for (int mf = 0; mf < 4; ++mf)
        af[mf] = *(const bf16x8*)&As[(wm + mf * 16 + q) * 64 + 8 * ((4 * s + g) ^ qx7)];
#pragma unroll
      for (int nf = 0; nf < 4; ++nf)
        bfr[nf] = *(const bf16x8*)&Bs[(wn + nf * 16 + q) * 64 + 8 * ((4 * s + g) ^ qx7)];
#pragma unroll
      for (int mf = 0; mf < 4; ++mf)
#pragma unroll
        for (int nf = 0; nf < 4; ++nf)
          acc[mf][nf] = __builtin_amdgcn_mfma_f32_16x16x32_bf16(af[mf], bfr[nf], acc[mf][nf], 0, 0, 0);
    }
    __syncthreads();
  }
  if (OUT_MODE == 0) {
    unsigned short* C = (unsigned short*)Cp;
#pragma unroll
    for (int mf = 0; mf < 4; ++mf)
#pragma unroll
      for (int nf = 0; nf < 4; ++nf)
#pragma unroll
        for (int r = 0; r < 4; ++r) {
          int row = tm + wm + mf * 16 + 4 * g + r;
          int col = tn + wn + nf * 16 + q;
          C[(size_t)row * EMB + col] = f2bf(acc[mf][nf][r]);
        }
  } else if (OUT_MODE == 1) {
    unsigned short* C = (unsigned short*)Cp;
#pragma unroll
    for (int mf = 0; mf < 4; ++mf) {
      int m0 = tm + wm + mf * 16 + 4 * g;
      int b = m0 >> 11, l = m0 & 2047;
#pragma unroll
      for (int nf = 0; nf < 4; ++nf) {
        int n = tn + wn + nf * 16 + q;
        int h = n >> 6, dv = n & 63;
        uint2 w;
        w.x = cvtpk(acc[mf][nf][0], acc[mf][nf][1]);
        w.y = cvtpk(acc[mf][nf][2], acc[mf][nf][3]);
        *(uint2*)&C[(((size_t)b * NH + h) * 64 + dv) * SEQ + l] = w;
      }
    }
  } else {
    float* C = (float*)Cp;
#pragma unroll
    for (int mf = 0; mf < 4; ++mf)
#pragma unroll
      for (int nf = 0; nf < 4; ++nf)
#pragma unroll
        for (int r = 0; r < 4; ++r) {
          int row = tm + wm + mf * 16 + 4 * g + r;
          int col = tn + wn + nf * 16 + q;
          C[(size_t)row * EMB + col] = acc[mf][nf][r];
        }
  }
}

// ---------------- flash attention: 128q/block, KVBLK=128 staged, two 64-kv halves ----------------
// (R12-exact, validated at 76.7 us / absmax 0.0156)
__global__ __launch_bounds__(256) void attn_kernel(
    const unsigned short* Qb, const unsigned short* Kb, const unsigned short* VTb,
    const int* pad, unsigned short* Ob) {
  __shared__ __align__(16) unsigned short Ks[2][128 * 64];  // [kv][d], src-XOR-swizzled
  __shared__ __align__(16) unsigned short Vs[2][64 * 128];  // [dv][kv], src-XOR-swizzled
  __shared__ __align__(16) unsigned short Ps[4][32 * 64];   // per-wave P, XOR-swizzled
  int tid = threadIdx.x;
  int lane = tid & 63, wave = tid >> 6;
  int q = lane & 15, g = lane >> 4;
  int qx7 = q & 7;
  // decode: xcd-local position p: c descending (LPT), 8 (b,h) per XCD interleaved
  int lin = blockIdx.x;
  int xcd = lin & 7;
  int p = lin >> 3;                  // 0..127
  int c = 15 - (p >> 3);             // chunk index, largest first
  int bh = xcd * 8 + (p & 7);        // this XCD's 8 (b,h) pairs
  int b = bh >> 4, h = bh & 15;

  // per-64-tile "fully valid" bitmask, wave-uniform. Rare non-full tiles re-ballot inline.
  unsigned allvalid = 0;
#pragma unroll 8
  for (int t0 = 0; t0 < 32; ++t0) {
    int pv = pad[b * SEQ + t0 * 64 + lane];
    if (__ballot(pv != 0) == ~0ull) allvalid |= (1u << t0);
  }

  bf16x8 ones;
#pragma unroll
  for (int i = 0; i < 8; ++i) ones[i] = (short)0x3F80;  // bf16 1.0

  // staging bases: K tile rows have 8 chunks (d=64); V tile rows have 16 chunks (kv=128)
  int srow = tid >> 3, scb = tid & 7;                 // K staging: rows 0..31 (+32/iter)
  int ssw = 8 * (scb ^ (srow & 7));
  const unsigned short* Kbase = Kb + (size_t)b * SEQ * EMB + (size_t)srow * EMB + h * 64 + ssw;
  int srow16 = tid >> 4, scb16 = tid & 15;            // V staging: rows 0..15 (+16/iter)
  int ssw16 = 8 * (scb16 ^ (srow16 & 7));
  const unsigned short* Vbase = VTb + (((size_t)(b * NH + h)) * 64 + srow16) * SEQ + ssw16;

  int qbase = c * 128 + wave * 32;     // this wave's 32 q rows
  int qgA = qbase + q;                 // column block A rows
  int qgB = qbase + 16 + q;            // column block B rows
  const unsigned short* QrowA = Qb + ((size_t)(b * SEQ + qgA)) * EMB + h * 64;
  const unsigned short* QrowB = Qb + ((size_t)(b * SEQ + qgB)) * EMB + h * 64;
  bf16x8 qA0 = *(const bf16x8*)(QrowA + 8 * g);
  bf16x8 qA1 = *(const bf16x8*)(QrowA + 32 + 8 * g);
  bf16x8 qB0 = *(const bf16x8*)(QrowB + 8 * g);
  bf16x8 qB1 = *(const bf16x8*)(QrowB + 32 + 8 * g);

  f32x4 oA[4] = {}, oB[4] = {};
  f32x4 olA = {}, olB = {};
  float mA = 0.f, mB = 0.f;

  // prologue: stage 128-kv tile 0 into buf 0 (K: 4 iters, V: 4 iters)
#pragma unroll
  for (int it = 0; it < 4; ++it) {
    gload16(Kbase + (size_t)(it * 32) * EMB, &Ks[0][(tid + it * 256) * 8]);
    gload16(Vbase + (size_t)(it * 16) * SEQ, &Vs[0][(tid + it * 256) * 8]);
  }
  __syncthreads();

#pragma unroll 1
  for (int t = 0; t <= c; ++t) {
    int kvt = t * 128;
    int cur = t & 1;
    if (t < c) {
#pragma unroll
      for (int it = 0; it < 4; ++it) {
        gload16(Kbase + (size_t)(kvt + 128 + it * 32) * EMB, &Ks[cur ^ 1][(tid + it * 256) * 8]);
        gload16(Vbase + (size_t)(kvt + 128) + (size_t)(it * 16) * SEQ, &Vs[cur ^ 1][(tid + it * 256) * 8]);
      }
    }
#pragma unroll 1
    for (int half = 0; half < 2; ++half) {
      int kvh = kvt + half * 64;
      bool active = (kvh < qbase + 32);  // wave-uniform: skip fully-above-diagonal halves
      if (active) {
        int th = 2 * t + half;
        bool tilefull = (allvalid >> th) & 1;

        // QK for both column blocks; K fragments read once, used twice
        f32x4 sA[4], sB[4];
        f32x4 seedA = {-mA, -mA, -mA, -mA};
        f32x4 seedB = {-mB, -mB, -mB, -mB};
#pragma unroll
        for (int mf = 0; mf < 4; ++mf) { sA[mf] = seedA; sB[mf] = seedB; }
        __builtin_amdgcn_s_setprio(1);
#pragma unroll
        for (int s = 0; s < 2; ++s) {
#pragma unroll
          for (int mf = 0; mf < 4; ++mf) {
            bf16x8 kf = *(const bf16x8*)&Ks[cur][(half * 64 + mf * 16 + q) * 64 + 8 * ((4 * s + g) ^ qx7)];
            sA[mf] = __builtin_amdgcn_mfma_f32_16x16x32_bf16(kf, s ? qA1 : qA0, sA[mf], 0, 0, 0);
            sB[mf] = __builtin_amdgcn_mfma_f32_16x16x32_bf16(kf, s ? qB1 : qB0, sB[mf], 0, 0, 0);
          }
        }
        __builtin_amdgcn_s_setprio(0);

        // mask (diagonal or padded halves only; for active halves kvh <= qbase always)
        if ((kvh + 63 > qbase) || !tilefull) {
          unsigned long long pmask =
              tilefull ? ~0ull : __ballot(pad[b * SEQ + kvh + lane] != 0);
#pragma unroll
          for (int mf = 0; mf < 4; ++mf)
#pragma unroll
            for (int r = 0; r < 4; ++r) {
              int kvl = mf * 16 + 4 * g + r;
              int kvg = kvh + kvl;
              bool bit = (pmask >> kvl) & 1ULL;
              sA[mf][r] = (kvg <= qgA && bit) ? sA[mf][r] : -INFINITY;
              sB[mf][r] = (kvg <= qgB && bit) ? sB[mf][r] : -INFINITY;
            }
        }

        // ---- softmax block A (R8-exact) ----
        {
          float pvv[16];
#pragma unroll
          for (int mf = 0; mf < 4; ++mf)
#pragma unroll
            for (int r = 0; r < 4; ++r)
              pvv[mf * 4 + r] = __builtin_amdgcn_exp2f(sA[mf][r]);
          float t0 = fmaxf(fmaxf(sA[0][0], sA[0][1]), fmaxf(sA[0][2], sA[0][3]));
          float t1 = fmaxf(fmaxf(sA[1][0], sA[1][1]), fmaxf(sA[1][2], sA[1][3]));
          float t2 = fmaxf(fmaxf(sA[2][0], sA[2][1]), fmaxf(sA[2][2], sA[2][3]));
          float t3 = fmaxf(fmaxf(sA[3][0], sA[3][1]), fmaxf(sA[3][2], sA[3][3]));
          float tl = fmaxf(fmaxf(t0, t1), fmaxf(t2, t3));
          if (!__all(tl <= 8.0f)) {
            float tmax = fmaxf(tl, __shfl_xor(tl, 16));
            tmax = fmaxf(tmax, __shfl_xor(tmax, 32));
            float d = fmaxf(tmax, 0.f);
            float alpha = __builtin_amdgcn_exp2f(-d);
            olA *= alpha;
#pragma unroll
            for (int mv = 0; mv < 4; ++mv) oA[mv] *= alpha;
#pragma unroll
            for (int mf = 0; mf < 4; ++mf)
#pragma unroll
              for (int r = 0; r < 4; ++r) {
                sA[mf][r] -= d;
                pvv[mf * 4 + r] = __builtin_amdgcn_exp2f(sA[mf][r]);
              }
            mA += d;
          }
#pragma unroll
          for (int mf = 0; mf < 4; ++mf) {
            uint2 w;
            w.x = cvtpk(pvv[mf * 4 + 0], pvv[mf * 4 + 1]);
            w.y = cvtpk(pvv[mf * 4 + 2], pvv[mf * 4 + 3]);
            int cbP = 2 * mf + (g >> 1);
            *(uint2*)&Ps[wave][q * 64 + 8 * (cbP ^ qx7) + 4 * (g & 1)] = w;
          }
        }
        // ---- softmax block B (R8-exact) ----
        {
          float pvv[16];
#pragma unroll
          for (int mf = 0; mf < 4; ++mf)
#pragma unroll
            for (int r = 0; r < 4; ++r)
              pvv[mf * 4 + r] = __builtin_amdgcn_exp2f(sB[mf][r]);
          float t0 = fmaxf(fmaxf(sB[0][0], sB[0][1]), fmaxf(sB[0][2], sB[0][3]));
          float t1 = fmaxf(fmaxf(sB[1][0], sB[1][1]), fmaxf(sB[1][2], sB[1][3]));
          float t2 = fmaxf(fmaxf(sB[2][0], sB[2][1]), fmaxf(sB[2][2], sB[2][3]));
          float t3 = fmaxf(fmaxf(sB[3][0], sB[3][1]), fmaxf(sB[3][2], sB[3][3]));
          float tl = fmaxf(fmaxf(t0, t1), fmaxf(t2, t3));
          if (!__all(tl <= 8.0f)) {
            float tmax = fmaxf(tl, __shfl_xor(tl, 16));
            tmax = fmaxf(tmax, __shfl_xor(tmax, 32));
            float d = fmaxf(tmax, 0.f);
            float alpha = __builtin_amdgcn_exp2f(-d);
            olB *= alpha;
#pragma unroll
            for (int mv = 0; mv < 4; ++mv) oB[mv] *= alpha;
#pragma unroll
            for (int mf = 0; mf < 4; ++mf)
#pragma unroll
              for (int r = 0; r < 4; ++r) {
                sB[mf][r] -= d;
                pvv[mf * 4 + r] = __builtin_amdgcn_exp2f(sB[mf][r]);
              }
            mB += d;
          }
#pragma unroll
          for (int mf = 0; mf < 4; ++mf) {
            uint2 w;
            w.x = cvtpk(pvv[mf * 4 + 0], pvv[mf * 4 + 1]);
            w.y = cvtpk(pvv[mf * 4 + 2], pvv[mf * 4 + 3]);
            int cbP = 2 * mf + (g >> 1);
            *(uint2*)&Ps[wave][(16 + q) * 64 + 8 * (cbP ^ qx7) + 4 * (g & 1)] = w;
          }
        }

        // PV: V fragments read once, used for both column blocks; l via ones-MFMA
        __builtin_amdgcn_s_setprio(1);
#pragma unroll
        for (int s = 0; s < 2; ++s) {
          bf16x8 pbA = *(const bf16x8*)&Ps[wave][q * 64 + 8 * ((4 * s + g) ^ qx7)];
          bf16x8 pbB = *(const bf16x8*)&Ps[wave][(16 + q) * 64 + 8 * ((4 * s + g) ^ qx7)];
#pragma unroll
          for (int mv = 0; mv < 4; ++mv) {
            bf16x8 va = *(const bf16x8*)&Vs[cur][(mv * 16 + q) * 128 + 8 * ((half * 8 + 4 * s + g) ^ qx7)];
            oA[mv] = __builtin_amdgcn_mfma_f32_16x16x32_bf16(va, pbA, oA[mv], 0, 0, 0);
            oB[mv] = __builtin_amdgcn_mfma_f32_16x16x32_bf16(va, pbB, oB[mv], 0, 0, 0);
          }
          olA = __builtin_amdgcn_mfma_f32_16x16x32_bf16(ones, pbA, olA, 0, 0, 0);
          olB = __builtin_amdgcn_mfma_f32_16x16x32_bf16(ones, pbB, olB, 0, 0, 0);
        }
        __builtin_amdgcn_s_setprio(0);
      }
    }
    __syncthreads();  // publishes next buf, protects cur for overwrite at t+2
  }

  float invA = 1.0f / olA[0];
  float invB = 1.0f / olB[0];
  unsigned short* OrowA = Ob + ((size_t)(b * SEQ + qgA)) * EMB + h * 64;
  unsigned short* OrowB = Ob + ((size_t)(b * SEQ + qgB)) * EMB + h * 64;
#pragma unroll
  for (int mv = 0; mv < 4; ++mv) {
    uint2 wa, wb;
    wa.x = cvtpk(oA[mv][0] * invA, oA[mv][1] * invA);
    wa.y = cvtpk(oA[mv][2] * invA, oA[mv][3] * invA);
    wb.x = cvtpk(oB[mv][0] * invB, oB[mv][1] * invB);
    wb.y = cvtpk(oB[mv][2] * invB, oB[mv][3] * invB);
    *(uint2*)&OrowA[mv * 16 + 4 * g] = wa;
    *(uint2*)&OrowB[mv * 16 + 4 * g] = wb;
  }
}

extern "C" void kernel_launch(void* const* d_in, const int* in_sizes, int n_in,
                              void* d_out, int out_size, void* d_ws, size_t ws_size,
                              hipStream_t stream) {
  const float* query = (const float*)d_in[0];
  const float* key   = (const float*)d_in[1];
  const float* value = (const float*)d_in[2];
  const int*   pad   = (const int*)d_in[3];
  const float* Wq = (const float*)d_in[4];
  const float* Wk = (const float*)d_in[5];
  const float* Wv = (const float*)d_in[6];
  const float* Wo = (const float*)d_in[7];

  unsigned short* WqT = (unsigned short*)d_ws;
  unsigned short* WkT = WqT + (size_t)EMB * EMB;
  unsigned short* WvT = WkT + (size_t)EMB * EMB;
  unsigned short* WoT = WvT + (size_t)EMB * EMB;
  unsigned short* Qb  = WoT + (size_t)EMB * EMB;
  unsigned short* Kb  = Qb + (size_t)MROWS * EMB;
  unsigned short* VTb = Kb + (size_t)MROWS * EMB;
  unsigned short* Ab  = VTb + (size_t)MROWS * EMB;

  wtrans_kernel<<<dim3(EMB / 32, EMB / 32, 4), dim3(32, 8), 0, stream>>>(
      Wq, Wk, Wv, Wo, WqT, WkT, WvT, WoT);
  gemm_kernel<1, 0><<<dim3(8, 64), 256, 0, stream>>>(query, WqT, Qb);
  gemm_kernel<1, 0><<<dim3(8, 64), 256, 0, stream>>>(key, WkT, Kb);
  gemm_kernel<1, 1><<<dim3(8, 64), 256, 0, stream>>>(value, WvT, VTb);
  attn_kernel<<<dim3(1024), 256, 0, stream>>>(Qb, Kb, VTb, pad, Ab);
  gemm_kernel<0, 2><<<dim3(8, 64), 256, 0, stream>>>(Ab, WoT, (float*)d_out);
}

// Round 15
// 179.146 us; speedup vs baseline: 1.1063x; 1.1063x over previous
//
#include <hip/hip_runtime.h>
#include <hip/hip_bf16.h>

typedef short bf16x8 __attribute__((ext_vector_type(8)));
typedef float f32x4 __attribute__((ext_vector_type(4)));

#define EMB 1024
#define NH 16
#define SEQ 2048
#define BATCH 4
#define MROWS (BATCH * SEQ)

static __device__ inline unsigned short f2bf(float f) {
  unsigned u = __float_as_uint(f);
  u += 0x7fffu + ((u >> 16) & 1u);
  return (unsigned short)(u >> 16);
}

static __device__ inline unsigned cvtpk(float lo, float hi) {
  unsigned r;
  asm("v_cvt_pk_bf16_f32 %0, %1, %2" : "=v"(r) : "v"(lo), "v"(hi));
  return r;
}

static __device__ inline void gload16(const void* g, void* l) {
  __builtin_amdgcn_global_load_lds(
      (const __attribute__((address_space(1))) unsigned int*)g,
      (__attribute__((address_space(3))) unsigned int*)l, 16, 0, 0);
}

// ---------------- weight transpose + cast: W[k][n] f32 -> WT[n][k] bf16 ----------------
// z==0 (Wq) additionally folds in 0.125*log2(e) so attention logits are in exp2 domain.
__global__ __launch_bounds__(256) void wtrans_kernel(
    const float* w0, const float* w1, const float* w2, const float* w3,
    unsigned short* o0, unsigned short* o1, unsigned short* o2, unsigned short* o3) {
  __shared__ float t[32][33];
  int z = blockIdx.z;
  const float* W = z == 0 ? w0 : z == 1 ? w1 : z == 2 ? w2 : w3;
  unsigned short* O = z == 0 ? o0 : z == 1 ? o1 : z == 2 ? o2 : o3;
  float sc = (z == 0) ? 0.18033688011112042f : 1.0f;
  int bx = blockIdx.x * 32;  // k block
  int by = blockIdx.y * 32;  // n block
  int tx = threadIdx.x, ty = threadIdx.y;  // (32,8)
#pragma unroll
  for (int j = 0; j < 4; ++j)
    t[ty + j * 8][tx] = W[(size_t)(bx + ty + j * 8) * EMB + by + tx];
  __syncthreads();
#pragma unroll
  for (int j = 0; j < 4; ++j)
    O[(size_t)(by + ty + j * 8) * EMB + bx + tx] = f2bf(t[tx][ty + j * 8] * sc);
}

// ---------------- merged QKV projection GEMM (single launch; z-slices dispatch in order) ----------------
// z=0: Q = query*WqT (bf16 [m][n]); z=1: K = key*WkT; z=2: V = value*WvT, V-transposed out.
__global__ __launch_bounds__(256) void qkv_gemm(
    const float* qry, const float* key, const float* val,
    const unsigned short* WqT, const unsigned short* WkT, const unsigned short* WvT,
    unsigned short* Qb, unsigned short* Kb, unsigned short* VTb) {
  __shared__ __align__(16) unsigned short As[128 * 64];  // XOR-swizzled cols
  __shared__ __align__(16) unsigned short Bs[128 * 64];
  const int K = EMB;
  int z = blockIdx.z;
  const float* A = z == 0 ? qry : z == 1 ? key : val;
  const unsigned short* Bt = z == 0 ? WqT : z == 1 ? WkT : WvT;
  int tid = threadIdx.x;
  int lane = tid & 63, wave = tid >> 6;
  int q = lane & 15, g = lane >> 4;
  int qx7 = q & 7;
  int wm = (wave >> 1) * 64, wn = (wave & 1) * 64;
  int lin = blockIdx.x + (blockIdx.y << 3);
  int idx = (lin & 7) * 64 + (lin >> 3);
  int tm = (idx >> 3) * 128, tn = (idx & 7) * 128;
  f32x4 acc[4][4] = {};
  for (int kt = 0; kt < K; kt += 64) {
#pragma unroll
    for (int it = 0; it < 4; ++it) {
      int gid = tid + it * 256;
      int row = gid >> 3, cb = gid & 7;
      const float4* s0 = (const float4*)(A + (size_t)(tm + row) * K + kt + cb * 8);
      float4 x = s0[0], y = s0[1];
      uint4 w;
      w.x = cvtpk(x.x, x.y); w.y = cvtpk(x.z, x.w);
      w.z = cvtpk(y.x, y.y); w.w = cvtpk(y.z, y.w);
      *(uint4*)&As[row * 64 + 8 * (cb ^ (row & 7))] = w;
    }
#pragma unroll
    for (int it = 0; it < 4; ++it) {
      int gid = tid + it * 256;
      int row = gid >> 3, cb = gid & 7;
      gload16(Bt + (size_t)(tn + row) * K + kt + 8 * (cb ^ (row & 7)), &Bs[gid * 8]);
    }
    __syncthreads();
#pragma unroll
    for (int s = 0; s < 2; ++s) {
      bf16x8 af[4], bfr[4];
#pragma unroll
      for (int mf = 0; mf < 4; ++mf)
        af[mf] = *(const bf16x8*)&As[(wm + mf * 16 + q) * 64 + 8 * ((4 * s + g) ^ qx7)];
#pragma unroll
      for (int nf = 0; nf < 4; ++nf)
        bfr[nf] = *(const bf16x8*)&Bs[(wn + nf * 16 + q) * 64 + 8 * ((4 * s + g) ^ qx7)];
#pragma unroll
      for (int mf = 0; mf < 4; ++mf)
#pragma unroll
        for (int nf = 0; nf < 4; ++nf)
          acc[mf][nf] = __builtin_amdgcn_mfma_f32_16x16x32_bf16(af[mf], bfr[nf], acc[mf][nf], 0, 0, 0);
    }
    __syncthreads();
  }
  if (z != 2) {
    unsigned short* C = z == 0 ? Qb : Kb;
#pragma unroll
    for (int mf = 0; mf < 4; ++mf)
#pragma unroll
      for (int nf = 0; nf < 4; ++nf) {
        int row = tm + wm + mf * 16 + 4 * g;
        int col = tn + wn + nf * 16 + q;
        uint2 w;
        w.x = cvtpk(acc[mf][nf][0], acc[mf][nf][1]);
        w.y = cvtpk(acc[mf][nf][2], acc[mf][nf][3]);
        C[(size_t)(row + 0) * EMB + col] = (unsigned short)(w.x & 0xffff);
        C[(size_t)(row + 1) * EMB + col] = (unsigned short)(w.x >> 16);
        C[(size_t)(row + 2) * EMB + col] = (unsigned short)(w.y & 0xffff);
        C[(size_t)(row + 3) * EMB + col] = (unsigned short)(w.y >> 16);
      }
  } else {
    unsigned short* C = VTb;
#pragma unroll
    for (int mf = 0; mf < 4; ++mf) {
      int m0 = tm + wm + mf * 16 + 4 * g;
      int b = m0 >> 11, l = m0 & 2047;
#pragma unroll
      for (int nf = 0; nf < 4; ++nf) {
        int n = tn + wn + nf * 16 + q;
        int h = n >> 6, dv = n & 63;
        uint2 w;
        w.x = cvtpk(acc[mf][nf][0], acc[mf][nf][1]);
        w.y = cvtpk(acc[mf][nf][2], acc[mf][nf][3]);
        *(uint2*)&C[(((size_t)b * NH + h) * 64 + dv) * SEQ + l] = w;
      }
    }
  }
}

// ---------------- final GEMM: out[M][1024] f32 = Ab[M][1024](bf16) * WoT^T ----------------
__global__ __launch_bounds__(256) void out_gemm(const unsigned short* Ab, const unsigned short* Bt, float* Cp) {
  __shared__ __align__(16) unsigned short As[128 * 64];
  __shared__ __align__(16) unsigned short Bs[128 * 64];
  const int K = EMB;
  int tid = threadIdx.x;
  int lane = tid & 63, wave = tid >> 6;
  int q = lane & 15, g = lane >> 4;
  int qx7 = q & 7;
  int wm = (wave >> 1) * 64, wn = (wave & 1) * 64;
  int lin = blockIdx.x + (blockIdx.y << 3);
  int idx = (lin & 7) * 64 + (lin >> 3);
  int tm = (idx >> 3) * 128, tn = (idx & 7) * 128;
  f32x4 acc[4][4] = {};
  for (int kt = 0; kt < K; kt += 64) {
#pragma unroll
    for (int it = 0; it < 4; ++it) {
      int gid = tid + it * 256;
      int row = gid >> 3, cb = gid & 7;
      gload16(Ab + (size_t)(tm + row) * K + kt + 8 * (cb ^ (row & 7)), &As[gid * 8]);
      gload16(Bt + (size_t)(tn + row) * K + kt + 8 * (cb ^ (row & 7)), &Bs[gid * 8]);
    }
    __syncthreads();
#pragma unroll
    for (int s = 0; s < 2; ++s) {
      bf16x8 af[4], bfr[4];
#pragma unroll
      for (int mf = 0; mf < 4; ++mf)
        af[mf] = *(const bf16x8*)&As[(wm + mf * 16 + q) * 64 + 8 * ((4 * s + g) ^ qx7)];
#pragma unroll
      for (int nf = 0; nf < 4; ++nf)
        bfr[nf] = *(const bf16x8*)&Bs[(wn + nf * 16 + q) * 64 + 8 * ((4 * s + g) ^ qx7)];
#pragma unroll
      for (int mf = 0; mf < 4; ++mf)
#pragma unroll
        for (int nf = 0; nf < 4; ++nf)
          acc[mf][nf] = __builtin_amdgcn_mfma_f32_16x16x32_bf16(af[mf], bfr[nf], acc[mf][nf], 0, 0, 0);
    }
    __syncthreads();
  }
#pragma unroll
  for (int mf = 0; mf < 4; ++mf)
#pragma unroll
    for (int nf = 0; nf < 4; ++nf)
#pragma unroll
      for (int r = 0; r < 4; ++r) {
        int row = tm + wm + mf * 16 + 4 * g + r;
        int col = tn + wn + nf * 16 + q;
        Cp[(size_t)row * EMB + col] = acc[mf][nf][r];
      }
}

// ---------------- flash attention: 128q/block, KVBLK=128 staged, two 64-kv halves ----------------
// (R12-exact, validated at 76.7 us / absmax 0.0156)
__global__ __launch_bounds__(256) void attn_kernel(
    const unsigned short* Qb, const unsigned short* Kb, const unsigned short* VTb,
    const int* pad, unsigned short* Ob) {
  __shared__ __align__(16) unsigned short Ks[2][128 * 64];  // [kv][d], src-XOR-swizzled
  __shared__ __align__(16) unsigned short Vs[2][64 * 128];  // [dv][kv], src-XOR-swizzled
  __shared__ __align__(16) unsigned short Ps[4][32 * 64];   // per-wave P, XOR-swizzled
  int tid = threadIdx.x;
  int lane = tid & 63, wave = tid >> 6;
  int q = lane & 15, g = lane >> 4;
  int qx7 = q & 7;
  // decode: xcd-local position p: c descending (LPT), 8 (b,h) per XCD interleaved
  int lin = blockIdx.x;
  int xcd = lin & 7;
  int p = lin >> 3;                  // 0..127
  int c = 15 - (p >> 3);             // chunk index, largest first
  int bh = xcd * 8 + (p & 7);        // this XCD's 8 (b,h) pairs
  int b = bh >> 4, h = bh & 15;

  // per-64-tile "fully valid" bitmask, wave-uniform. Rare non-full tiles re-ballot inline.
  unsigned allvalid = 0;
#pragma unroll 8
  for (int t0 = 0; t0 < 32; ++t0) {
    int pv = pad[b * SEQ + t0 * 64 + lane];
    if (__ballot(pv != 0) == ~0ull) allvalid |= (1u << t0);
  }

  bf16x8 ones;
#pragma unroll
  for (int i = 0; i < 8; ++i) ones[i] = (short)0x3F80;  // bf16 1.0

  // staging bases: K tile rows have 8 chunks (d=64); V tile rows have 16 chunks (kv=128)
  int srow = tid >> 3, scb = tid & 7;                 // K staging: rows 0..31 (+32/iter)
  int ssw = 8 * (scb ^ (srow & 7));
  const unsigned short* Kbase = Kb + (size_t)b * SEQ * EMB + (size_t)srow * EMB + h * 64 + ssw;
  int srow16 = tid >> 4, scb16 = tid & 15;            // V staging: rows 0..15 (+16/iter)
  int ssw16 = 8 * (scb16 ^ (srow16 & 7));
  const unsigned short* Vbase = VTb + (((size_t)(b * NH + h)) * 64 + srow16) * SEQ + ssw16;

  int qbase = c * 128 + wave * 32;     // this wave's 32 q rows
  int qgA = qbase + q;                 // column block A rows
  int qgB = qbase + 16 + q;            // column block B rows
  const unsigned short* QrowA = Qb + ((size_t)(b * SEQ + qgA)) * EMB + h * 64;
  const unsigned short* QrowB = Qb + ((size_t)(b * SEQ + qgB)) * EMB + h * 64;
  bf16x8 qA0 = *(const bf16x8*)(QrowA + 8 * g);
  bf16x8 qA1 = *(const bf16x8*)(QrowA + 32 + 8 * g);
  bf16x8 qB0 = *(const bf16x8*)(QrowB + 8 * g);
  bf16x8 qB1 = *(const bf16x8*)(QrowB + 32 + 8 * g);

  f32x4 oA[4] = {}, oB[4] = {};
  f32x4 olA = {}, olB = {};
  float mA = 0.f, mB = 0.f;

  // prologue: stage 128-kv tile 0 into buf 0 (K: 4 iters, V: 4 iters)
#pragma unroll
  for (int it = 0; it < 4; ++it) {
    gload16(Kbase + (size_t)(it * 32) * EMB, &Ks[0][(tid + it * 256) * 8]);
    gload16(Vbase + (size_t)(it * 16) * SEQ, &Vs[0][(tid + it * 256) * 8]);
  }
  __syncthreads();

#pragma unroll 1
  for (int t = 0; t <= c; ++t) {
    int kvt = t * 128;
    int cur = t & 1;
    if (t < c) {
#pragma unroll
      for (int it = 0; it < 4; ++it) {
        gload16(Kbase + (size_t)(kvt + 128 + it * 32) * EMB, &Ks[cur ^ 1][(tid + it * 256) * 8]);
        gload16(Vbase + (size_t)(kvt + 128) + (size_t)(it * 16) * SEQ, &Vs[cur ^ 1][(tid + it * 256) * 8]);
      }
    }
#pragma unroll 1
    for (int half = 0; half < 2; ++half) {
      int kvh = kvt + half * 64;
      bool active = (kvh < qbase + 32);  // wave-uniform: skip fully-above-diagonal halves
      if (active) {
        int th = 2 * t + half;
        bool tilefull = (allvalid >> th) & 1;

        // QK for both column blocks; K fragments read once, used twice
        f32x4 sA[4], sB[4];
        f32x4 seedA = {-mA, -mA, -mA, -mA};
        f32x4 seedB = {-mB, -mB, -mB, -mB};
#pragma unroll
        for (int mf = 0; mf < 4; ++mf) { sA[mf] = seedA; sB[mf] = seedB; }
        __builtin_amdgcn_s_setprio(1);
#pragma unroll
        for (int s = 0; s < 2; ++s) {
#pragma unroll
          for (int mf = 0; mf < 4; ++mf) {
            bf16x8 kf = *(const bf16x8*)&Ks[cur][(half * 64 + mf * 16 + q) * 64 + 8 * ((4 * s + g) ^ qx7)];
            sA[mf] = __builtin_amdgcn_mfma_f32_16x16x32_bf16(kf, s ? qA1 : qA0, sA[mf], 0, 0, 0);
            sB[mf] = __builtin_amdgcn_mfma_f32_16x16x32_bf16(kf, s ? qB1 : qB0, sB[mf], 0, 0, 0);
          }
        }
        __builtin_amdgcn_s_setprio(0);

        // mask (diagonal or padded halves only; for active halves kvh <= qbase always)
        if ((kvh + 63 > qbase) || !tilefull) {
          unsigned long long pmask =
              tilefull ? ~0ull : __ballot(pad[b * SEQ + kvh + lane] != 0);
#pragma unroll
          for (int mf = 0; mf < 4; ++mf)
#pragma unroll
            for (int r = 0; r < 4; ++r) {
              int kvl = mf * 16 + 4 * g + r;
              int kvg = kvh + kvl;
              bool bit = (pmask >> kvl) & 1ULL;
              sA[mf][r] = (kvg <= qgA && bit) ? sA[mf][r] : -INFINITY;
              sB[mf][r] = (kvg <= qgB && bit) ? sB[mf][r] : -INFINITY;
            }
        }

        // ---- softmax block A (R8-exact) ----
        {
          float pvv[16];
#pragma unroll
          for (int mf = 0; mf < 4; ++mf)
#pragma unroll
            for (int r = 0; r < 4; ++r)
              pvv[mf * 4 + r] = __builtin_amdgcn_exp2f(sA[mf][r]);
          float t0 = fmaxf(fmaxf(sA[0][0], sA[0][1]), fmaxf(sA[0][2], sA[0][3]));
          float t1 = fmaxf(fmaxf(sA[1][0], sA[1][1]), fmaxf(sA[1][2], sA[1][3]));
          float t2 = fmaxf(fmaxf(sA[2][0], sA[2][1]), fmaxf(sA[2][2], sA[2][3]));
          float t3 = fmaxf(fmaxf(sA[3][0], sA[3][1]), fmaxf(sA[3][2], sA[3][3]));
          float tl = fmaxf(fmaxf(t0, t1), fmaxf(t2, t3));
          if (!__all(tl <= 8.0f)) {
            float tmax = fmaxf(tl, __shfl_xor(tl, 16));
            tmax = fmaxf(tmax, __shfl_xor(tmax, 32));
            float d = fmaxf(tmax, 0.f);
            float alpha = __builtin_amdgcn_exp2f(-d);
            olA *= alpha;
#pragma unroll
            for (int mv = 0; mv < 4; ++mv) oA[mv] *= alpha;
#pragma unroll
            for (int mf = 0; mf < 4; ++mf)
#pragma unroll
              for (int r = 0; r < 4; ++r) {
                sA[mf][r] -= d;
                pvv[mf * 4 + r] = __builtin_amdgcn_exp2f(sA[mf][r]);
              }
            mA += d;
          }
#pragma unroll
          for (int mf = 0; mf < 4; ++mf) {
            uint2 w;
            w.x = cvtpk(pvv[mf * 4 + 0], pvv[mf * 4 + 1]);
            w.y = cvtpk(pvv[mf * 4 + 2], pvv[mf * 4 + 3]);
            int cbP = 2 * mf + (g >> 1);
            *(uint2*)&Ps[wave][q * 64 + 8 * (cbP ^ qx7) + 4 * (g & 1)] = w;
          }
        }
        // ---- softmax block B (R8-exact) ----
        {
          float pvv[16];
#pragma unroll
          for (int mf = 0; mf < 4; ++mf)
#pragma unroll
            for (int r = 0; r < 4; ++r)
              pvv[mf * 4 + r] = __builtin_amdgcn_exp2f(sB[mf][r]);
          float t0 = fmaxf(fmaxf(sB[0][0], sB[0][1]), fmaxf(sB[0][2], sB[0][3]));
          float t1 = fmaxf(fmaxf(sB[1][0], sB[1][1]), fmaxf(sB[1][2], sB[1][3]));
          float t2 = fmaxf(fmaxf(sB[2][0], sB[2][1]), fmaxf(sB[2][2], sB[2][3]));
          float t3 = fmaxf(fmaxf(sB[3][0], sB[3][1]), fmaxf(sB[3][2], sB[3][3]));
          float tl = fmaxf(fmaxf(t0, t1), fmaxf(t2, t3));
          if (!__all(tl <= 8.0f)) {
            float tmax = fmaxf(tl, __shfl_xor(tl, 16));
            tmax = fmaxf(tmax, __shfl_xor(tmax, 32));
            float d = fmaxf(tmax, 0.f);
            float alpha = __builtin_amdgcn_exp2f(-d);
            olB *= alpha;
#pragma unroll
            for (int mv = 0; mv < 4; ++mv) oB[mv] *= alpha;
#pragma unroll
            for (int mf = 0; mf < 4; ++mf)
#pragma unroll
              for (int r = 0; r < 4; ++r) {
                sB[mf][r] -= d;
                pvv[mf * 4 + r] = __builtin_amdgcn_exp2f(sB[mf][r]);
              }
            mB += d;
          }
#pragma unroll
          for (int mf = 0; mf < 4; ++mf) {
            uint2 w;
            w.x = cvtpk(pvv[mf * 4 + 0], pvv[mf * 4 + 1]);
            w.y = cvtpk(pvv[mf * 4 + 2], pvv[mf * 4 + 3]);
            int cbP = 2 * mf + (g >> 1);
            *(uint2*)&Ps[wave][(16 + q) * 64 + 8 * (cbP ^ qx7) + 4 * (g & 1)] = w;
          }
        }

        // PV: V fragments read once, used for both column blocks; l via ones-MFMA
        __builtin_amdgcn_s_setprio(1);
#pragma unroll
        for (int s = 0; s < 2; ++s) {
          bf16x8 pbA = *(const bf16x8*)&Ps[wave][q * 64 + 8 * ((4 * s + g) ^ qx7)];
          bf16x8 pbB = *(const bf16x8*)&Ps[wave][(16 + q) * 64 + 8 * ((4 * s + g) ^ qx7)];
#pragma unroll
          for (int mv = 0; mv < 4; ++mv) {
            bf16x8 va = *(const bf16x8*)&Vs[cur][(mv * 16 + q) * 128 + 8 * ((half * 8 + 4 * s + g) ^ qx7)];
            oA[mv] = __builtin_amdgcn_mfma_f32_16x16x32_bf16(va, pbA, oA[mv], 0, 0, 0);
            oB[mv] = __builtin_amdgcn_mfma_f32_16x16x32_bf16(va, pbB, oB[mv], 0, 0, 0);
          }
          olA = __builtin_amdgcn_mfma_f32_16x16x32_bf16(ones, pbA, olA, 0, 0, 0);
          olB = __builtin_amdgcn_mfma_f32_16x16x32_bf16(ones, pbB, olB, 0, 0, 0);
        }
        __builtin_amdgcn_s_setprio(0);
      }
    }
    __syncthreads();  // publishes next buf, protects cur for overwrite at t+2
  }

  float invA = 1.0f / olA[0];
  float invB = 1.0f / olB[0];
  unsigned short* OrowA = Ob + ((size_t)(b * SEQ + qgA)) * EMB + h * 64;
  unsigned short* OrowB = Ob + ((size_t)(b * SEQ + qgB)) * EMB + h * 64;
#pragma unroll
  for (int mv = 0; mv < 4; ++mv) {
    uint2 wa, wb;
    wa.x = cvtpk(oA[mv][0] * invA, oA[mv][1] * invA);
    wa.y = cvtpk(oA[mv][2] * invA, oA[mv][3] * invA);
    wb.x = cvtpk(oB[mv][0] * invB, oB[mv][1] * invB);
    wb.y = cvtpk(oB[mv][2] * invB, oB[mv][3] * invB);
    *(uint2*)&OrowA[mv * 16 + 4 * g] = wa;
    *(uint2*)&OrowB[mv * 16 + 4 * g] = wb;
  }
}

extern "C" void kernel_launch(void* const* d_in, const int* in_sizes, int n_in,
                              void* d_out, int out_size, void* d_ws, size_t ws_size,
                              hipStream_t stream) {
  const float* query = (const float*)d_in[0];
  const float* key   = (const float*)d_in[1];
  const float* value = (const float*)d_in[2];
  const int*   pad   = (const int*)d_in[3];
  const float* Wq = (const float*)d_in[4];
  const float* Wk = (const float*)d_in[5];
  const float* Wv = (const float*)d_in[6];
  const float* Wo = (const float*)d_in[7];

  unsigned short* WqT = (unsigned short*)d_ws;
  unsigned short* WkT = WqT + (size_t)EMB * EMB;
  unsigned short* WvT = WkT + (size_t)EMB * EMB;
  unsigned short* WoT = WvT + (size_t)EMB * EMB;
  unsigned short* Qb  = WoT + (size_t)EMB * EMB;
  unsigned short* Kb  = Qb + (size_t)MROWS * EMB;
  unsigned short* VTb = Kb + (size_t)MROWS * EMB;
  unsigned short* Ab  = VTb + (size_t)MROWS * EMB;

  wtrans_kernel<<<dim3(EMB / 32, EMB / 32, 4), dim3(32, 8), 0, stream>>>(
      Wq, Wk, Wv, Wo, WqT, WkT, WvT, WoT);
  qkv_gemm<<<dim3(8, 64, 3), 256, 0, stream>>>(query, key, value, WqT, WkT, WvT, Qb, Kb, VTb);
  attn_kernel<<<dim3(1024), 256, 0, stream>>>(Qb, Kb, VTb, pad, Ab);
  out_gemm<<<dim3(8, 64), 256, 0, stream>>>(Ab, WoT, (float*)d_out);
}

// Round 16
// 176.996 us; speedup vs baseline: 1.1197x; 1.0121x over previous
//
#include <hip/hip_runtime.h>
#include <hip/hip_bf16.h>

typedef short bf16x8 __attribute__((ext_vector_type(8)));
typedef float f32x4 __attribute__((ext_vector_type(4)));

#define EMB 1024
#define NH 16
#define SEQ 2048
#define BATCH 4
#define MROWS (BATCH * SEQ)

static __device__ inline unsigned short f2bf(float f) {
  unsigned u = __float_as_uint(f);
  u += 0x7fffu + ((u >> 16) & 1u);
  return (unsigned short)(u >> 16);
}

static __device__ inline unsigned cvtpk(float lo, float hi) {
  unsigned r;
  asm("v_cvt_pk_bf16_f32 %0, %1, %2" : "=v"(r) : "v"(lo), "v"(hi));
  return r;
}

static __device__ inline void gload16(const void* g, void* l) {
  __builtin_amdgcn_global_load_lds(
      (const __attribute__((address_space(1))) unsigned int*)g,
      (__attribute__((address_space(3))) unsigned int*)l, 16, 0, 0);
}

// max of 16 values, max3-friendly shape (nested fmaxf triples -> v_max3_f32)
static __device__ inline float max16(const f32x4* s) {
  float m0 = fmaxf(fmaxf(s[0][0], s[0][1]), s[0][2]);
  float m1 = fmaxf(fmaxf(s[0][3], s[1][0]), s[1][1]);
  float m2 = fmaxf(fmaxf(s[1][2], s[1][3]), s[2][0]);
  float m3 = fmaxf(fmaxf(s[2][1], s[2][2]), s[2][3]);
  float m4 = fmaxf(fmaxf(s[3][0], s[3][1]), s[3][2]);
  float n0 = fmaxf(fmaxf(m0, m1), m2);
  float n1 = fmaxf(fmaxf(m3, m4), s[3][3]);
  return fmaxf(n0, n1);
}

// ---------------- weight transpose + cast: W[k][n] f32 -> WT[n][k] bf16 ----------------
// z==0 (Wq) additionally folds in 0.125*log2(e) so attention logits are in exp2 domain.
__global__ __launch_bounds__(256) void wtrans_kernel(
    const float* w0, const float* w1, const float* w2, const float* w3,
    unsigned short* o0, unsigned short* o1, unsigned short* o2, unsigned short* o3) {
  __shared__ float t[32][33];
  int z = blockIdx.z;
  const float* W = z == 0 ? w0 : z == 1 ? w1 : z == 2 ? w2 : w3;
  unsigned short* O = z == 0 ? o0 : z == 1 ? o1 : z == 2 ? o2 : o3;
  float sc = (z == 0) ? 0.18033688011112042f : 1.0f;
  int bx = blockIdx.x * 32;  // k block
  int by = blockIdx.y * 32;  // n block
  int tx = threadIdx.x, ty = threadIdx.y;  // (32,8)
#pragma unroll
  for (int j = 0; j < 4; ++j)
    t[ty + j * 8][tx] = W[(size_t)(bx + ty + j * 8) * EMB + by + tx];
  __syncthreads();
#pragma unroll
  for (int j = 0; j < 4; ++j)
    O[(size_t)(by + ty + j * 8) * EMB + bx + tx] = f2bf(t[tx][ty + j * 8] * sc);
}

// ---------------- merged QKV projection GEMM (single launch) ----------------
// z=0: Q = query*WqT (bf16 [m][n]); z=1: K = key*WkT; z=2: V = value*WvT, V-transposed out.
__global__ __launch_bounds__(256) void qkv_gemm(
    const float* qry, const float* key, const float* val,
    const unsigned short* WqT, const unsigned short* WkT, const unsigned short* WvT,
    unsigned short* Qb, unsigned short* Kb, unsigned short* VTb) {
  __shared__ __align__(16) unsigned short As[128 * 64];  // XOR-swizzled cols
  __shared__ __align__(16) unsigned short Bs[128 * 64];
  const int K = EMB;
  int z = blockIdx.z;
  const float* A = z == 0 ? qry : z == 1 ? key : val;
  const unsigned short* Bt = z == 0 ? WqT : z == 1 ? WkT : WvT;
  int tid = threadIdx.x;
  int lane = tid & 63, wave = tid >> 6;
  int q = lane & 15, g = lane >> 4;
  int qx7 = q & 7;
  int wm = (wave >> 1) * 64, wn = (wave & 1) * 64;
  int lin = blockIdx.x + (blockIdx.y << 3);
  int idx = (lin & 7) * 64 + (lin >> 3);
  int tm = (idx >> 3) * 128, tn = (idx & 7) * 128;
  f32x4 acc[4][4] = {};
  for (int kt = 0; kt < K; kt += 64) {
#pragma unroll
    for (int it = 0; it < 4; ++it) {
      int gid = tid + it * 256;
      int row = gid >> 3, cb = gid & 7;
      const float4* s0 = (const float4*)(A + (size_t)(tm + row) * K + kt + cb * 8);
      float4 x = s0[0], y = s0[1];
      uint4 w;
      w.x = cvtpk(x.x, x.y); w.y = cvtpk(x.z, x.w);
      w.z = cvtpk(y.x, y.y); w.w = cvtpk(y.z, y.w);
      *(uint4*)&As[row * 64 + 8 * (cb ^ (row & 7))] = w;
    }
#pragma unroll
    for (int it = 0; it < 4; ++it) {
      int gid = tid + it * 256;
      int row = gid >> 3, cb = gid & 7;
      gload16(Bt + (size_t)(tn + row) * K + kt + 8 * (cb ^ (row & 7)), &Bs[gid * 8]);
    }
    __syncthreads();
#pragma unroll
    for (int s = 0; s < 2; ++s) {
      bf16x8 af[4], bfr[4];
#pragma unroll
      for (int mf = 0; mf < 4; ++mf)
        af[mf] = *(const bf16x8*)&As[(wm + mf * 16 + q) * 64 + 8 * ((4 * s + g) ^ qx7)];
#pragma unroll
      for (int nf = 0; nf < 4; ++nf)
        bfr[nf] = *(const bf16x8*)&Bs[(wn + nf * 16 + q) * 64 + 8 * ((4 * s + g) ^ qx7)];
#pragma unroll
      for (int mf = 0; mf < 4; ++mf)
#pragma unroll
        for (int nf = 0; nf < 4; ++nf)
          acc[mf][nf] = __builtin_amdgcn_mfma_f32_16x16x32_bf16(af[mf], bfr[nf], acc[mf][nf], 0, 0, 0);
    }
    __syncthreads();
  }
  if (z != 2) {
    unsigned short* C = z == 0 ? Qb : Kb;
#pragma unroll
    for (int mf = 0; mf < 4; ++mf)
#pragma unroll
      for (int nf = 0; nf < 4; ++nf) {
        int row = tm + wm + mf * 16 + 4 * g;
        int col = tn + wn + nf * 16 + q;
        uint2 w;
        w.x = cvtpk(acc[mf][nf][0], acc[mf][nf][1]);
        w.y = cvtpk(acc[mf][nf][2], acc[mf][nf][3]);
        C[(size_t)(row + 0) * EMB + col] = (unsigned short)(w.x & 0xffff);
        C[(size_t)(row + 1) * EMB + col] = (unsigned short)(w.x >> 16);
        C[(size_t)(row + 2) * EMB + col] = (unsigned short)(w.y & 0xffff);
        C[(size_t)(row + 3) * EMB + col] = (unsigned short)(w.y >> 16);
      }
  } else {
    unsigned short* C = VTb;
#pragma unroll
    for (int mf = 0; mf < 4; ++mf) {
      int m0 = tm + wm + mf * 16 + 4 * g;
      int b = m0 >> 11, l = m0 & 2047;
#pragma unroll
      for (int nf = 0; nf < 4; ++nf) {
        int n = tn + wn + nf * 16 + q;
        int h = n >> 6, dv = n & 63;
        uint2 w;
        w.x = cvtpk(acc[mf][nf][0], acc[mf][nf][1]);
        w.y = cvtpk(acc[mf][nf][2], acc[mf][nf][3]);
        *(uint2*)&C[(((size_t)b * NH + h) * 64 + dv) * SEQ + l] = w;
      }
    }
  }
}

// ---------------- final GEMM: out[M][1024] f32 = Ab[M][1024](bf16) * WoT^T ----------------
__global__ __launch_bounds__(256) void out_gemm(const unsigned short* Ab, const unsigned short* Bt, float* Cp) {
  __shared__ __align__(16) unsigned short As[128 * 64];
  __shared__ __align__(16) unsigned short Bs[128 * 64];
  const int K = EMB;
  int tid = threadIdx.x;
  int lane = tid & 63, wave = tid >> 6;
  int q = lane & 15, g = lane >> 4;
  int qx7 = q & 7;
  int wm = (wave >> 1) * 64, wn = (wave & 1) * 64;
  int lin = blockIdx.x + (blockIdx.y << 3);
  int idx = (lin & 7) * 64 + (lin >> 3);
  int tm = (idx >> 3) * 128, tn = (idx & 7) * 128;
  f32x4 acc[4][4] = {};
  for (int kt = 0; kt < K; kt += 64) {
#pragma unroll
    for (int it = 0; it < 4; ++it) {
      int gid = tid + it * 256;
      int row = gid >> 3, cb = gid & 7;
      gload16(Ab + (size_t)(tm + row) * K + kt + 8 * (cb ^ (row & 7)), &As[gid * 8]);
      gload16(Bt + (size_t)(tn + row) * K + kt + 8 * (cb ^ (row & 7)), &Bs[gid * 8]);
    }
    __syncthreads();
#pragma unroll
    for (int s = 0; s < 2; ++s) {
      bf16x8 af[4], bfr[4];
#pragma unroll
      for (int mf = 0; mf < 4; ++mf)
        af[mf] = *(const bf16x8*)&As[(wm + mf * 16 + q) * 64 + 8 * ((4 * s + g) ^ qx7)];
#pragma unroll
      for (int nf = 0; nf < 4; ++nf)
        bfr[nf] = *(const bf16x8*)&Bs[(wn + nf * 16 + q) * 64 + 8 * ((4 * s + g) ^ qx7)];
#pragma unroll
      for (int mf = 0; mf < 4; ++mf)
#pragma unroll
        for (int nf = 0; nf < 4; ++nf)
          acc[mf][nf] = __builtin_amdgcn_mfma_f32_16x16x32_bf16(af[mf], bfr[nf], acc[mf][nf], 0, 0, 0);
    }
    __syncthreads();
  }
#pragma unroll
  for (int mf = 0; mf < 4; ++mf)
#pragma unroll
    for (int nf = 0; nf < 4; ++nf)
#pragma unroll
      for (int r = 0; r < 4; ++r) {
        int row = tm + wm + mf * 16 + 4 * g + r;
        int col = tn + wn + nf * 16 + q;
        Cp[(size_t)row * EMB + col] = acc[mf][nf][r];
      }
}

// ---------------- flash attention: 128q/block, KVBLK=128, R12 numerics + micro-sched ----------------
// Q,K bf16 [b][l][h*64+d] (Q pre-scaled by 0.125*log2e); VT bf16 [b][h][dv][l]; out bf16.
// Micro-opts vs R12 (exact transforms only): max3-shaped max trees; pb LDS reads issued
// early (after each softmax's Ps writes) so the LDS round-trip hides under the other
// softmax's VALU work.
__global__ __launch_bounds__(256) void attn_kernel(
    const unsigned short* Qb, const unsigned short* Kb, const unsigned short* VTb,
    const int* pad, unsigned short* Ob) {
  __shared__ __align__(16) unsigned short Ks[2][128 * 64];  // [kv][d], src-XOR-swizzled
  __shared__ __align__(16) unsigned short Vs[2][64 * 128];  // [dv][kv], src-XOR-swizzled
  __shared__ __align__(16) unsigned short Ps[4][32 * 64];   // per-wave P, XOR-swizzled
  int tid = threadIdx.x;
  int lane = tid & 63, wave = tid >> 6;
  int q = lane & 15, g = lane >> 4;
  int qx7 = q & 7;
  // decode: xcd-local position p: c descending (LPT), 8 (b,h) per XCD interleaved
  int lin = blockIdx.x;
  int xcd = lin & 7;
  int p = lin >> 3;                  // 0..127
  int c = 15 - (p >> 3);             // chunk index, largest first
  int bh = xcd * 8 + (p & 7);        // this XCD's 8 (b,h) pairs
  int b = bh >> 4, h = bh & 15;

  // per-64-tile "fully valid" bitmask, wave-uniform. Rare non-full tiles re-ballot inline.
  unsigned allvalid = 0;
#pragma unroll 8
  for (int t0 = 0; t0 < 32; ++t0) {
    int pv = pad[b * SEQ + t0 * 64 + lane];
    if (__ballot(pv != 0) == ~0ull) allvalid |= (1u << t0);
  }

  bf16x8 ones;
#pragma unroll
  for (int i = 0; i < 8; ++i) ones[i] = (short)0x3F80;  // bf16 1.0

  // staging bases: K tile rows have 8 chunks (d=64); V tile rows have 16 chunks (kv=128)
  int srow = tid >> 3, scb = tid & 7;                 // K staging: rows 0..31 (+32/iter)
  int ssw = 8 * (scb ^ (srow & 7));
  const unsigned short* Kbase = Kb + (size_t)b * SEQ * EMB + (size_t)srow * EMB + h * 64 + ssw;
  int srow16 = tid >> 4, scb16 = tid & 15;            // V staging: rows 0..15 (+16/iter)
  int ssw16 = 8 * (scb16 ^ (srow16 & 7));
  const unsigned short* Vbase = VTb + (((size_t)(b * NH + h)) * 64 + srow16) * SEQ + ssw16;

  int qbase = c * 128 + wave * 32;     // this wave's 32 q rows
  int qgA = qbase + q;                 // column block A rows
  int qgB = qbase + 16 + q;            // column block B rows
  const unsigned short* QrowA = Qb + ((size_t)(b * SEQ + qgA)) * EMB + h * 64;
  const unsigned short* QrowB = Qb + ((size_t)(b * SEQ + qgB)) * EMB + h * 64;
  bf16x8 qA0 = *(const bf16x8*)(QrowA + 8 * g);
  bf16x8 qA1 = *(const bf16x8*)(QrowA + 32 + 8 * g);
  bf16x8 qB0 = *(const bf16x8*)(QrowB + 8 * g);
  bf16x8 qB1 = *(const bf16x8*)(QrowB + 32 + 8 * g);

  f32x4 oA[4] = {}, oB[4] = {};
  f32x4 olA = {}, olB = {};
  float mA = 0.f, mB = 0.f;

  // prologue: stage 128-kv tile 0 into buf 0 (K: 4 iters, V: 4 iters)
#pragma unroll
  for (int it = 0; it < 4; ++it) {
    gload16(Kbase + (size_t)(it * 32) * EMB, &Ks[0][(tid + it * 256) * 8]);
    gload16(Vbase + (size_t)(it * 16) * SEQ, &Vs[0][(tid + it * 256) * 8]);
  }
  __syncthreads();

#pragma unroll 1
  for (int t = 0; t <= c; ++t) {
    int kvt = t * 128;
    int cur = t & 1;
    if (t < c) {
#pragma unroll
      for (int it = 0; it < 4; ++it) {
        gload16(Kbase + (size_t)(kvt + 128 + it * 32) * EMB, &Ks[cur ^ 1][(tid + it * 256) * 8]);
        gload16(Vbase + (size_t)(kvt + 128) + (size_t)(it * 16) * SEQ, &Vs[cur ^ 1][(tid + it * 256) * 8]);
      }
    }
#pragma unroll 1
    for (int half = 0; half < 2; ++half) {
      int kvh = kvt + half * 64;
      bool active = (kvh < qbase + 32);  // wave-uniform: skip fully-above-diagonal halves
      if (active) {
        int th = 2 * t + half;
        bool tilefull = (allvalid >> th) & 1;

        // QK for both column blocks; K fragments read once, used twice
        f32x4 sA[4], sB[4];
        f32x4 seedA = {-mA, -mA, -mA, -mA};
        f32x4 seedB = {-mB, -mB, -mB, -mB};
#pragma unroll
        for (int mf = 0; mf < 4; ++mf) { sA[mf] = seedA; sB[mf] = seedB; }
        __builtin_amdgcn_s_setprio(1);
#pragma unroll
        for (int s = 0; s < 2; ++s) {
#pragma unroll
          for (int mf = 0; mf < 4; ++mf) {
            bf16x8 kf = *(const bf16x8*)&Ks[cur][(half * 64 + mf * 16 + q) * 64 + 8 * ((4 * s + g) ^ qx7)];
            sA[mf] = __builtin_amdgcn_mfma_f32_16x16x32_bf16(kf, s ? qA1 : qA0, sA[mf], 0, 0, 0);
            sB[mf] = __builtin_amdgcn_mfma_f32_16x16x32_bf16(kf, s ? qB1 : qB0, sB[mf], 0, 0, 0);
          }
        }
        __builtin_amdgcn_s_setprio(0);

        // mask (diagonal or padded halves only; for active halves kvh <= qbase always)
        if ((kvh + 63 > qbase) || !tilefull) {
          unsigned long long pmask =
              tilefull ? ~0ull : __ballot(pad[b * SEQ + kvh + lane] != 0);
#pragma unroll
          for (int mf = 0; mf < 4; ++mf)
#pragma unroll
            for (int r = 0; r < 4; ++r) {
              int kvl = mf * 16 + 4 * g + r;
              int kvg = kvh + kvl;
              bool bit = (pmask >> kvl) & 1ULL;
              sA[mf][r] = (kvg <= qgA && bit) ? sA[mf][r] : -INFINITY;
              sB[mf][r] = (kvg <= qgB && bit) ? sB[mf][r] : -INFINITY;
            }
        }

        bf16x8 pbA0, pbA1, pbB0, pbB1;

        // ---- softmax block A (R8-exact numerics) ----
        {
          float pvv[16];
#pragma unroll
          for (int mf = 0; mf < 4; ++mf)
#pragma unroll
            for (int r = 0; r < 4; ++r)
              pvv[mf * 4 + r] = __builtin_amdgcn_exp2f(sA[mf][r]);
          float tl = max16(sA);
          if (!__all(tl <= 8.0f)) {
            float tmax = fmaxf(tl, __shfl_xor(tl, 16));
            tmax = fmaxf(tmax, __shfl_xor(tmax, 32));
            float d = fmaxf(tmax, 0.f);
            float alpha = __builtin_amdgcn_exp2f(-d);
            olA *= alpha;
#pragma unroll
            for (int mv = 0; mv < 4; ++mv) oA[mv] *= alpha;
#pragma unroll
            for (int mf = 0; mf < 4; ++mf)
#pragma unroll
              for (int r = 0; r < 4; ++r) {
                sA[mf][r] -= d;
                pvv[mf * 4 + r] = __builtin_amdgcn_exp2f(sA[mf][r]);
              }
            mA += d;
          }
#pragma unroll
          for (int mf = 0; mf < 4; ++mf) {
            uint2 w;
            w.x = cvtpk(pvv[mf * 4 + 0], pvv[mf * 4 + 1]);
            w.y = cvtpk(pvv[mf * 4 + 2], pvv[mf * 4 + 3]);
            int cbP = 2 * mf + (g >> 1);
            *(uint2*)&Ps[wave][q * 64 + 8 * (cbP ^ qx7) + 4 * (g & 1)] = w;
          }
          // issue pbA reads now; LDS round-trip hides under softmax B
          pbA0 = *(const bf16x8*)&Ps[wave][q * 64 + 8 * ((4 * 0 + g) ^ qx7)];
          pbA1 = *(const bf16x8*)&Ps[wave][q * 64 + 8 * ((4 * 1 + g) ^ qx7)];
        }
        // ---- softmax block B (R8-exact numerics) ----
        {
          float pvv[16];
#pragma unroll
          for (int mf = 0; mf < 4; ++mf)
#pragma unroll
            for (int r = 0; r < 4; ++r)
              pvv[mf * 4 + r] = __builtin_amdgcn_exp2f(sB[mf][r]);
          float tl = max16(sB);
          if (!__all(tl <= 8.0f)) {
            float tmax = fmaxf(tl, __shfl_xor(tl, 16));
            tmax = fmaxf(tmax, __shfl_xor(tmax, 32));
            float d = fmaxf(tmax, 0.f);
            float alpha = __builtin_amdgcn_exp2f(-d);
            olB *= alpha;
#pragma unroll
            for (int mv = 0; mv < 4; ++mv) oB[mv] *= alpha;
#pragma unroll
            for (int mf = 0; mf < 4; ++mf)
#pragma unroll
              for (int r = 0; r < 4; ++r) {
                sB[mf][r] -= d;
                pvv[mf * 4 + r] = __builtin_amdgcn_exp2f(sB[mf][r]);
              }
            mB += d;
          }
#pragma unroll
          for (int mf = 0; mf < 4; ++mf) {
            uint2 w;
            w.x = cvtpk(pvv[mf * 4 + 0], pvv[mf * 4 + 1]);
            w.y = cvtpk(pvv[mf * 4 + 2], pvv[mf * 4 + 3]);
            int cbP = 2 * mf + (g >> 1);
            *(uint2*)&Ps[wave][(16 + q) * 64 + 8 * (cbP ^ qx7) + 4 * (g & 1)] = w;
          }
          pbB0 = *(const bf16x8*)&Ps[wave][(16 + q) * 64 + 8 * ((4 * 0 + g) ^ qx7)];
          pbB1 = *(const bf16x8*)&Ps[wave][(16 + q) * 64 + 8 * ((4 * 1 + g) ^ qx7)];
        }

        // PV: V fragments read once, used for both column blocks; l via ones-MFMA
        __builtin_amdgcn_s_setprio(1);
#pragma unroll
        for (int s = 0; s < 2; ++s) {
          bf16x8 pbA = s ? pbA1 : pbA0;
          bf16x8 pbB = s ? pbB1 : pbB0;
#pragma unroll
          for (int mv = 0; mv < 4; ++mv) {
            bf16x8 va = *(const bf16x8*)&Vs[cur][(mv * 16 + q) * 128 + 8 * ((half * 8 + 4 * s + g) ^ qx7)];
            oA[mv] = __builtin_amdgcn_mfma_f32_16x16x32_bf16(va, pbA, oA[mv], 0, 0, 0);
            oB[mv] = __builtin_amdgcn_mfma_f32_16x16x32_bf16(va, pbB, oB[mv], 0, 0, 0);
          }
          olA = __builtin_amdgcn_mfma_f32_16x16x32_bf16(ones, pbA, olA, 0, 0, 0);
          olB = __builtin_amdgcn_mfma_f32_16x16x32_bf16(ones, pbB, olB, 0, 0, 0);
        }
        __builtin_amdgcn_s_setprio(0);
      }
    }
    __syncthreads();  // publishes next buf, protects cur for overwrite at t+2
  }

  float invA = 1.0f / olA[0];
  float invB = 1.0f / olB[0];
  unsigned short* OrowA = Ob + ((size_t)(b * SEQ + qgA)) * EMB + h * 64;
  unsigned short* OrowB = Ob + ((size_t)(b * SEQ + qgB)) * EMB + h * 64;
#pragma unroll
  for (int mv = 0; mv < 4; ++mv) {
    uint2 wa, wb;
    wa.x = cvtpk(oA[mv][0] * invA, oA[mv][1] * invA);
    wa.y = cvtpk(oA[mv][2] * invA, oA[mv][3] * invA);
    wb.x = cvtpk(oB[mv][0] * invB, oB[mv][1] * invB);
    wb.y = cvtpk(oB[mv][2] * invB, oB[mv][3] * invB);
    *(uint2*)&OrowA[mv * 16 + 4 * g] = wa;
    *(uint2*)&OrowB[mv * 16 + 4 * g] = wb;
  }
}

extern "C" void kernel_launch(void* const* d_in, const int* in_sizes, int n_in,
                              void* d_out, int out_size, void* d_ws, size_t ws_size,
                              hipStream_t stream) {
  const float* query = (const float*)d_in[0];
  const float* key   = (const float*)d_in[1];
  const float* value = (const float*)d_in[2];
  const int*   pad   = (const int*)d_in[3];
  const float* Wq = (const float*)d_in[4];
  const float* Wk = (const float*)d_in[5];
  const float* Wv = (const float*)d_in[6];
  const float* Wo = (const float*)d_in[7];

  unsigned short* WqT = (unsigned short*)d_ws;
  unsigned short* WkT = WqT + (size_t)EMB * EMB;
  unsigned short* WvT = WkT + (size_t)EMB * EMB;
  unsigned short* WoT = WvT + (size_t)EMB * EMB;
  unsigned short* Qb  = WoT + (size_t)EMB * EMB;
  unsigned short* Kb  = Qb + (size_t)MROWS * EMB;
  unsigned short* VTb = Kb + (size_t)MROWS * EMB;
  unsigned short* Ab  = VTb + (size_t)MROWS * EMB;

  wtrans_kernel<<<dim3(EMB / 32, EMB / 32, 4), dim3(32, 8), 0, stream>>>(
      Wq, Wk, Wv, Wo, WqT, WkT, WvT, WoT);
  qkv_gemm<<<dim3(8, 64, 3), 256, 0, stream>>>(query, key, value, WqT, WkT, WvT, Qb, Kb, VTb);
  attn_kernel<<<dim3(1024), 256, 0, stream>>>(Qb, Kb, VTb, pad, Ab);
  out_gemm<<<dim3(8, 64), 256, 0, stream>>>(Ab, WoT, (float*)d_out);
}

// Round 17
// 174.457 us; speedup vs baseline: 1.1360x; 1.0146x over previous
//
#include <hip/hip_runtime.h>
#include <hip/hip_bf16.h>

typedef short bf16x8 __attribute__((ext_vector_type(8)));
typedef float f32x4 __attribute__((ext_vector_type(4)));

#define EMB 1024
#define NH 16
#define SEQ 2048
#define BATCH 4
#define MROWS (BATCH * SEQ)

static __device__ inline unsigned short f2bf(float f) {
  unsigned u = __float_as_uint(f);
  u += 0x7fffu + ((u >> 16) & 1u);
  return (unsigned short)(u >> 16);
}

static __device__ inline unsigned cvtpk(float lo, float hi) {
  unsigned r;
  asm("v_cvt_pk_bf16_f32 %0, %1, %2" : "=v"(r) : "v"(lo), "v"(hi));
  return r;
}

static __device__ inline void gload16(const void* g, void* l) {
  __builtin_amdgcn_global_load_lds(
      (const __attribute__((address_space(1))) unsigned int*)g,
      (__attribute__((address_space(3))) unsigned int*)l, 16, 0, 0);
}

// max of 16 values, max3-friendly shape (nested fmaxf triples -> v_max3_f32)
static __device__ inline float max16(const f32x4* s) {
  float m0 = fmaxf(fmaxf(s[0][0], s[0][1]), s[0][2]);
  float m1 = fmaxf(fmaxf(s[0][3], s[1][0]), s[1][1]);
  float m2 = fmaxf(fmaxf(s[1][2], s[1][3]), s[2][0]);
  float m3 = fmaxf(fmaxf(s[2][1], s[2][2]), s[2][3]);
  float m4 = fmaxf(fmaxf(s[3][0], s[3][1]), s[3][2]);
  float n0 = fmaxf(fmaxf(m0, m1), m2);
  float n1 = fmaxf(fmaxf(m3, m4), s[3][3]);
  return fmaxf(n0, n1);
}

// ---------------- weight transpose + cast: W[k][n] f32 -> WT[n][k] bf16 ----------------
// z==0 (Wq) additionally folds in 0.125*log2(e) so attention logits are in exp2 domain.
__global__ __launch_bounds__(256) void wtrans_kernel(
    const float* w0, const float* w1, const float* w2, const float* w3,
    unsigned short* o0, unsigned short* o1, unsigned short* o2, unsigned short* o3) {
  __shared__ float t[32][33];
  int z = blockIdx.z;
  const float* W = z == 0 ? w0 : z == 1 ? w1 : z == 2 ? w2 : w3;
  unsigned short* O = z == 0 ? o0 : z == 1 ? o1 : z == 2 ? o2 : o3;
  float sc = (z == 0) ? 0.18033688011112042f : 1.0f;
  int bx = blockIdx.x * 32;  // k block
  int by = blockIdx.y * 32;  // n block
  int tx = threadIdx.x, ty = threadIdx.y;  // (32,8)
#pragma unroll
  for (int j = 0; j < 4; ++j)
    t[ty + j * 8][tx] = W[(size_t)(bx + ty + j * 8) * EMB + by + tx];
  __syncthreads();
#pragma unroll
  for (int j = 0; j < 4; ++j)
    O[(size_t)(by + ty + j * 8) * EMB + bx + tx] = f2bf(t[tx][ty + j * 8] * sc);
}

// ---------------- merged QKV projection GEMM (single launch) ----------------
// z=0: Q = query*WqT (bf16 [m][n]); z=1: K = key*WkT; z=2: V = value*WvT, V-transposed out.
// Per K-step: B's async gload16 issued FIRST, then A's f32 load+cvtpk+ds_write overlaps
// B's in-flight DMA (pure reorder vs R16; zero numerics change).
__global__ __launch_bounds__(256) void qkv_gemm(
    const float* qry, const float* key, const float* val,
    const unsigned short* WqT, const unsigned short* WkT, const unsigned short* WvT,
    unsigned short* Qb, unsigned short* Kb, unsigned short* VTb) {
  __shared__ __align__(16) unsigned short As[128 * 64];  // XOR-swizzled cols
  __shared__ __align__(16) unsigned short Bs[128 * 64];
  const int K = EMB;
  int z = blockIdx.z;
  const float* A = z == 0 ? qry : z == 1 ? key : val;
  const unsigned short* Bt = z == 0 ? WqT : z == 1 ? WkT : WvT;
  int tid = threadIdx.x;
  int lane = tid & 63, wave = tid >> 6;
  int q = lane & 15, g = lane >> 4;
  int qx7 = q & 7;
  int wm = (wave >> 1) * 64, wn = (wave & 1) * 64;
  int lin = blockIdx.x + (blockIdx.y << 3);
  int idx = (lin & 7) * 64 + (lin >> 3);
  int tm = (idx >> 3) * 128, tn = (idx & 7) * 128;
  f32x4 acc[4][4] = {};
  for (int kt = 0; kt < K; kt += 64) {
    // B first: async DMA starts immediately
#pragma unroll
    for (int it = 0; it < 4; ++it) {
      int gid = tid + it * 256;
      int row = gid >> 3, cb = gid & 7;
      gload16(Bt + (size_t)(tn + row) * K + kt + 8 * (cb ^ (row & 7)), &Bs[gid * 8]);
    }
    // A: f32 load + cvtpk + ds_write overlaps B's in-flight DMA
#pragma unroll
    for (int it = 0; it < 4; ++it) {
      int gid = tid + it * 256;
      int row = gid >> 3, cb = gid & 7;
      const float4* s0 = (const float4*)(A + (size_t)(tm + row) * K + kt + cb * 8);
      float4 x = s0[0], y = s0[1];
      uint4 w;
      w.x = cvtpk(x.x, x.y); w.y = cvtpk(x.z, x.w);
      w.z = cvtpk(y.x, y.y); w.w = cvtpk(y.z, y.w);
      *(uint4*)&As[row * 64 + 8 * (cb ^ (row & 7))] = w;
    }
    __syncthreads();
#pragma unroll
    for (int s = 0; s < 2; ++s) {
      bf16x8 af[4], bfr[4];
#pragma unroll
      for (int mf = 0; mf < 4; ++mf)
        af[mf] = *(const bf16x8*)&As[(wm + mf * 16 + q) * 64 + 8 * ((4 * s + g) ^ qx7)];
#pragma unroll
      for (int nf = 0; nf < 4; ++nf)
        bfr[nf] = *(const bf16x8*)&Bs[(wn + nf * 16 + q) * 64 + 8 * ((4 * s + g) ^ qx7)];
#pragma unroll
      for (int mf = 0; mf < 4; ++mf)
#pragma unroll
        for (int nf = 0; nf < 4; ++nf)
          acc[mf][nf] = __builtin_amdgcn_mfma_f32_16x16x32_bf16(af[mf], bfr[nf], acc[mf][nf], 0, 0, 0);
    }
    __syncthreads();
  }
  if (z != 2) {
    unsigned short* C = z == 0 ? Qb : Kb;
#pragma unroll
    for (int mf = 0; mf < 4; ++mf)
#pragma unroll
      for (int nf = 0; nf < 4; ++nf) {
        int row = tm + wm + mf * 16 + 4 * g;
        int col = tn + wn + nf * 16 + q;
        uint2 w;
        w.x = cvtpk(acc[mf][nf][0], acc[mf][nf][1]);
        w.y = cvtpk(acc[mf][nf][2], acc[mf][nf][3]);
        C[(size_t)(row + 0) * EMB + col] = (unsigned short)(w.x & 0xffff);
        C[(size_t)(row + 1) * EMB + col] = (unsigned short)(w.x >> 16);
        C[(size_t)(row + 2) * EMB + col] = (unsigned short)(w.y & 0xffff);
        C[(size_t)(row + 3) * EMB + col] = (unsigned short)(w.y >> 16);
      }
  } else {
    unsigned short* C = VTb;
#pragma unroll
    for (int mf = 0; mf < 4; ++mf) {
      int m0 = tm + wm + mf * 16 + 4 * g;
      int b = m0 >> 11, l = m0 & 2047;
#pragma unroll
      for (int nf = 0; nf < 4; ++nf) {
        int n = tn + wn + nf * 16 + q;
        int h = n >> 6, dv = n & 63;
        uint2 w;
        w.x = cvtpk(acc[mf][nf][0], acc[mf][nf][1]);
        w.y = cvtpk(acc[mf][nf][2], acc[mf][nf][3]);
        *(uint2*)&C[(((size_t)b * NH + h) * 64 + dv) * SEQ + l] = w;
      }
    }
  }
}

// ---------------- final GEMM: out[M][1024] f32 = Ab[M][1024](bf16) * WoT^T ----------------
__global__ __launch_bounds__(256) void out_gemm(const unsigned short* Ab, const unsigned short* Bt, float* Cp) {
  __shared__ __align__(16) unsigned short As[128 * 64];
  __shared__ __align__(16) unsigned short Bs[128 * 64];
  const int K = EMB;
  int tid = threadIdx.x;
  int lane = tid & 63, wave = tid >> 6;
  int q = lane & 15, g = lane >> 4;
  int qx7 = q & 7;
  int wm = (wave >> 1) * 64, wn = (wave & 1) * 64;
  int lin = blockIdx.x + (blockIdx.y << 3);
  int idx = (lin & 7) * 64 + (lin >> 3);
  int tm = (idx >> 3) * 128, tn = (idx & 7) * 128;
  f32x4 acc[4][4] = {};
  for (int kt = 0; kt < K; kt += 64) {
#pragma unroll
    for (int it = 0; it < 4; ++it) {
      int gid = tid + it * 256;
      int row = gid >> 3, cb = gid & 7;
      gload16(Ab + (size_t)(tm + row) * K + kt + 8 * (cb ^ (row & 7)), &As[gid * 8]);
      gload16(Bt + (size_t)(tn + row) * K + kt + 8 * (cb ^ (row & 7)), &Bs[gid * 8]);
    }
    __syncthreads();
#pragma unroll
    for (int s = 0; s < 2; ++s) {
      bf16x8 af[4], bfr[4];
#pragma unroll
      for (int mf = 0; mf < 4; ++mf)
        af[mf] = *(const bf16x8*)&As[(wm + mf * 16 + q) * 64 + 8 * ((4 * s + g) ^ qx7)];
#pragma unroll
      for (int nf = 0; nf < 4; ++nf)
        bfr[nf] = *(const bf16x8*)&Bs[(wn + nf * 16 + q) * 64 + 8 * ((4 * s + g) ^ qx7)];
#pragma unroll
      for (int mf = 0; mf < 4; ++mf)
#pragma unroll
        for (int nf = 0; nf < 4; ++nf)
          acc[mf][nf] = __builtin_amdgcn_mfma_f32_16x16x32_bf16(af[mf], bfr[nf], acc[mf][nf], 0, 0, 0);
    }
    __syncthreads();
  }
#pragma unroll
  for (int mf = 0; mf < 4; ++mf)
#pragma unroll
    for (int nf = 0; nf < 4; ++nf)
#pragma unroll
      for (int r = 0; r < 4; ++r) {
        int row = tm + wm + mf * 16 + 4 * g + r;
        int col = tn + wn + nf * 16 + q;
        Cp[(size_t)row * EMB + col] = acc[mf][nf][r];
      }
}

// ---------------- flash attention: 128q/block, KVBLK=128, R12 numerics + micro-sched ----------------
// Q,K bf16 [b][l][h*64+d] (Q pre-scaled by 0.125*log2e); VT bf16 [b][h][dv][l]; out bf16.
// vs R16 (all exact transforms): prologue staging issued before pad ballots + Q loads so
// those overlap the DMA; max3 trees; early pb reads.
__global__ __launch_bounds__(256) void attn_kernel(
    const unsigned short* Qb, const unsigned short* Kb, const unsigned short* VTb,
    const int* pad, unsigned short* Ob) {
  __shared__ __align__(16) unsigned short Ks[2][128 * 64];  // [kv][d], src-XOR-swizzled
  __shared__ __align__(16) unsigned short Vs[2][64 * 128];  // [dv][kv], src-XOR-swizzled
  __shared__ __align__(16) unsigned short Ps[4][32 * 64];   // per-wave P, XOR-swizzled
  int tid = threadIdx.x;
  int lane = tid & 63, wave = tid >> 6;
  int q = lane & 15, g = lane >> 4;
  int qx7 = q & 7;
  // decode: xcd-local position p: c descending (LPT), 8 (b,h) per XCD interleaved
  int lin = blockIdx.x;
  int xcd = lin & 7;
  int p = lin >> 3;                  // 0..127
  int c = 15 - (p >> 3);             // chunk index, largest first
  int bh = xcd * 8 + (p & 7);        // this XCD's 8 (b,h) pairs
  int b = bh >> 4, h = bh & 15;

  // staging bases: K tile rows have 8 chunks (d=64); V tile rows have 16 chunks (kv=128)
  int srow = tid >> 3, scb = tid & 7;                 // K staging: rows 0..31 (+32/iter)
  int ssw = 8 * (scb ^ (srow & 7));
  const unsigned short* Kbase = Kb + (size_t)b * SEQ * EMB + (size_t)srow * EMB + h * 64 + ssw;
  int srow16 = tid >> 4, scb16 = tid & 15;            // V staging: rows 0..15 (+16/iter)
  int ssw16 = 8 * (scb16 ^ (srow16 & 7));
  const unsigned short* Vbase = VTb + (((size_t)(b * NH + h)) * 64 + srow16) * SEQ + ssw16;

  // prologue: issue tile-0 staging FIRST; ballots and Q loads below overlap the DMA
#pragma unroll
  for (int it = 0; it < 4; ++it) {
    gload16(Kbase + (size_t)(it * 32) * EMB, &Ks[0][(tid + it * 256) * 8]);
    gload16(Vbase + (size_t)(it * 16) * SEQ, &Vs[0][(tid + it * 256) * 8]);
  }

  // per-64-tile "fully valid" bitmask, wave-uniform. Rare non-full tiles re-ballot inline.
  unsigned allvalid = 0;
#pragma unroll 8
  for (int t0 = 0; t0 < 32; ++t0) {
    int pv = pad[b * SEQ + t0 * 64 + lane];
    if (__ballot(pv != 0) == ~0ull) allvalid |= (1u << t0);
  }

  bf16x8 ones;
#pragma unroll
  for (int i = 0; i < 8; ++i) ones[i] = (short)0x3F80;  // bf16 1.0

  int qbase = c * 128 + wave * 32;     // this wave's 32 q rows
  int qgA = qbase + q;                 // column block A rows
  int qgB = qbase + 16 + q;            // column block B rows
  const unsigned short* QrowA = Qb + ((size_t)(b * SEQ + qgA)) * EMB + h * 64;
  const unsigned short* QrowB = Qb + ((size_t)(b * SEQ + qgB)) * EMB + h * 64;
  bf16x8 qA0 = *(const bf16x8*)(QrowA + 8 * g);
  bf16x8 qA1 = *(const bf16x8*)(QrowA + 32 + 8 * g);
  bf16x8 qB0 = *(const bf16x8*)(QrowB + 8 * g);
  bf16x8 qB1 = *(const bf16x8*)(QrowB + 32 + 8 * g);

  f32x4 oA[4] = {}, oB[4] = {};
  f32x4 olA = {}, olB = {};
  float mA = 0.f, mB = 0.f;

  __syncthreads();  // tile 0 staged

#pragma unroll 1
  for (int t = 0; t <= c; ++t) {
    int kvt = t * 128;
    int cur = t & 1;
    if (t < c) {
#pragma unroll
      for (int it = 0; it < 4; ++it) {
        gload16(Kbase + (size_t)(kvt + 128 + it * 32) * EMB, &Ks[cur ^ 1][(tid + it * 256) * 8]);
        gload16(Vbase + (size_t)(kvt + 128) + (size_t)(it * 16) * SEQ, &Vs[cur ^ 1][(tid + it * 256) * 8]);
      }
    }
#pragma unroll 1
    for (int half = 0; half < 2; ++half) {
      int kvh = kvt + half * 64;
      bool active = (kvh < qbase + 32);  // wave-uniform: skip fully-above-diagonal halves
      if (active) {
        int th = 2 * t + half;
        bool tilefull = (allvalid >> th) & 1;

        // QK for both column blocks; K fragments read once, used twice
        f32x4 sA[4], sB[4];
        f32x4 seedA = {-mA, -mA, -mA, -mA};
        f32x4 seedB = {-mB, -mB, -mB, -mB};
#pragma unroll
        for (int mf = 0; mf < 4; ++mf) { sA[mf] = seedA; sB[mf] = seedB; }
        __builtin_amdgcn_s_setprio(1);
#pragma unroll
        for (int s = 0; s < 2; ++s) {
#pragma unroll
          for (int mf = 0; mf < 4; ++mf) {
            bf16x8 kf = *(const bf16x8*)&Ks[cur][(half * 64 + mf * 16 + q) * 64 + 8 * ((4 * s + g) ^ qx7)];
            sA[mf] = __builtin_amdgcn_mfma_f32_16x16x32_bf16(kf, s ? qA1 : qA0, sA[mf], 0, 0, 0);
            sB[mf] = __builtin_amdgcn_mfma_f32_16x16x32_bf16(kf, s ? qB1 : qB0, sB[mf], 0, 0, 0);
          }
        }
        __builtin_amdgcn_s_setprio(0);

        // mask (diagonal or padded halves only; for active halves kvh <= qbase always)
        if ((kvh + 63 > qbase) || !tilefull) {
          unsigned long long pmask =
              tilefull ? ~0ull : __ballot(pad[b * SEQ + kvh + lane] != 0);
#pragma unroll
          for (int mf = 0; mf < 4; ++mf)
#pragma unroll
            for (int r = 0; r < 4; ++r) {
              int kvl = mf * 16 + 4 * g + r;
              int kvg = kvh + kvl;
              bool bit = (pmask >> kvl) & 1ULL;
              sA[mf][r] = (kvg <= qgA && bit) ? sA[mf][r] : -INFINITY;
              sB[mf][r] = (kvg <= qgB && bit) ? sB[mf][r] : -INFINITY;
            }
        }

        bf16x8 pbA0, pbA1, pbB0, pbB1;

        // ---- softmax block A (R8-exact numerics) ----
        {
          float pvv[16];
#pragma unroll
          for (int mf = 0; mf < 4; ++mf)
#pragma unroll
            for (int r = 0; r < 4; ++r)
              pvv[mf * 4 + r] = __builtin_amdgcn_exp2f(sA[mf][r]);
          float tl = max16(sA);
          if (!__all(tl <= 8.0f)) {
            float tmax = fmaxf(tl, __shfl_xor(tl, 16));
            tmax = fmaxf(tmax, __shfl_xor(tmax, 32));
            float d = fmaxf(tmax, 0.f);
            float alpha = __builtin_amdgcn_exp2f(-d);
            olA *= alpha;
#pragma unroll
            for (int mv = 0; mv < 4; ++mv) oA[mv] *= alpha;
#pragma unroll
            for (int mf = 0; mf < 4; ++mf)
#pragma unroll
              for (int r = 0; r < 4; ++r) {
                sA[mf][r] -= d;
                pvv[mf * 4 + r] = __builtin_amdgcn_exp2f(sA[mf][r]);
              }
            mA += d;
          }
#pragma unroll
          for (int mf = 0; mf < 4; ++mf) {
            uint2 w;
            w.x = cvtpk(pvv[mf * 4 + 0], pvv[mf * 4 + 1]);
            w.y = cvtpk(pvv[mf * 4 + 2], pvv[mf * 4 + 3]);
            int cbP = 2 * mf + (g >> 1);
            *(uint2*)&Ps[wave][q * 64 + 8 * (cbP ^ qx7) + 4 * (g & 1)] = w;
          }
          // issue pbA reads now; LDS round-trip hides under softmax B
          pbA0 = *(const bf16x8*)&Ps[wave][q * 64 + 8 * ((4 * 0 + g) ^ qx7)];
          pbA1 = *(const bf16x8*)&Ps[wave][q * 64 + 8 * ((4 * 1 + g) ^ qx7)];
        }
        // ---- softmax block B (R8-exact numerics) ----
        {
          float pvv[16];
#pragma unroll
          for (int mf = 0; mf < 4; ++mf)
#pragma unroll
            for (int r = 0; r < 4; ++r)
              pvv[mf * 4 + r] = __builtin_amdgcn_exp2f(sB[mf][r]);
          float tl = max16(sB);
          if (!__all(tl <= 8.0f)) {
            float tmax = fmaxf(tl, __shfl_xor(tl, 16));
            tmax = fmaxf(tmax, __shfl_xor(tmax, 32));
            float d = fmaxf(tmax, 0.f);
            float alpha = __builtin_amdgcn_exp2f(-d);
            olB *= alpha;
#pragma unroll
            for (int mv = 0; mv < 4; ++mv) oB[mv] *= alpha;
#pragma unroll
            for (int mf = 0; mf < 4; ++mf)
#pragma unroll
              for (int r = 0; r < 4; ++r) {
                sB[mf][r] -= d;
                pvv[mf * 4 + r] = __builtin_amdgcn_exp2f(sB[mf][r]);
              }
            mB += d;
          }
#pragma unroll
          for (int mf = 0; mf < 4; ++mf) {
            uint2 w;
            w.x = cvtpk(pvv[mf * 4 + 0], pvv[mf * 4 + 1]);
            w.y = cvtpk(pvv[mf * 4 + 2], pvv[mf * 4 + 3]);
            int cbP = 2 * mf + (g >> 1);
            *(uint2*)&Ps[wave][(16 + q) * 64 + 8 * (cbP ^ qx7) + 4 * (g & 1)] = w;
          }
          pbB0 = *(const bf16x8*)&Ps[wave][(16 + q) * 64 + 8 * ((4 * 0 + g) ^ qx7)];
          pbB1 = *(const bf16x8*)&Ps[wave][(16 + q) * 64 + 8 * ((4 * 1 + g) ^ qx7)];
        }

        // PV: V fragments read once, used for both column blocks; l via ones-MFMA
        __builtin_amdgcn_s_setprio(1);
#pragma unroll
        for (int s = 0; s < 2; ++s) {
          bf16x8 pbA = s ? pbA1 : pbA0;
          bf16x8 pbB = s ? pbB1 : pbB0;
#pragma unroll
          for (int mv = 0; mv < 4; ++mv) {
            bf16x8 va = *(const bf16x8*)&Vs[cur][(mv * 16 + q) * 128 + 8 * ((half * 8 + 4 * s + g) ^ qx7)];
            oA[mv] = __builtin_amdgcn_mfma_f32_16x16x32_bf16(va, pbA, oA[mv], 0, 0, 0);
            oB[mv] = __builtin_amdgcn_mfma_f32_16x16x32_bf16(va, pbB, oB[mv], 0, 0, 0);
          }
          olA = __builtin_amdgcn_mfma_f32_16x16x32_bf16(ones, pbA, olA, 0, 0, 0);
          olB = __builtin_amdgcn_mfma_f32_16x16x32_bf16(ones, pbB, olB, 0, 0, 0);
        }
        __builtin_amdgcn_s_setprio(0);
      }
    }
    __syncthreads();  // publishes next buf, protects cur for overwrite at t+2
  }

  float invA = 1.0f / olA[0];
  float invB = 1.0f / olB[0];
  unsigned short* OrowA = Ob + ((size_t)(b * SEQ + qgA)) * EMB + h * 64;
  unsigned short* OrowB = Ob + ((size_t)(b * SEQ + qgB)) * EMB + h * 64;
#pragma unroll
  for (int mv = 0; mv < 4; ++mv) {
    uint2 wa, wb;
    wa.x = cvtpk(oA[mv][0] * invA, oA[mv][1] * invA);
    wa.y = cvtpk(oA[mv][2] * invA, oA[mv][3] * invA);
    wb.x = cvtpk(oB[mv][0] * invB, oB[mv][1] * invB);
    wb.y = cvtpk(oB[mv][2] * invB, oB[mv][3] * invB);
    *(uint2*)&OrowA[mv * 16 + 4 * g] = wa;
    *(uint2*)&OrowB[mv * 16 + 4 * g] = wb;
  }
}

extern "C" void kernel_launch(void* const* d_in, const int* in_sizes, int n_in,
                              void* d_out, int out_size, void* d_ws, size_t ws_size,
                              hipStream_t stream) {
  const float* query = (const float*)d_in[0];
  const float* key   = (const float*)d_in[1];
  const float* value = (const float*)d_in[2];
  const int*   pad   = (const int*)d_in[3];
  const float* Wq = (const float*)d_in[4];
  const float* Wk = (const float*)d_in[5];
  const float* Wv = (const float*)d_in[6];
  const float* Wo = (const float*)d_in[7];

  unsigned short* WqT = (unsigned short*)d_ws;
  unsigned short* WkT = WqT + (size_t)EMB * EMB;
  unsigned short* WvT = WkT + (size_t)EMB * EMB;
  unsigned short* WoT = WvT + (size_t)EMB * EMB;
  unsigned short* Qb  = WoT + (size_t)EMB * EMB;
  unsigned short* Kb  = Qb + (size_t)MROWS * EMB;
  unsigned short* VTb = Kb + (size_t)MROWS * EMB;
  unsigned short* Ab  = VTb + (size_t)MROWS * EMB;

  wtrans_kernel<<<dim3(EMB / 32, EMB / 32, 4), dim3(32, 8), 0, stream>>>(
      Wq, Wk, Wv, Wo, WqT, WkT, WvT, WoT);
  qkv_gemm<<<dim3(8, 64, 3), 256, 0, stream>>>(query, key, value, WqT, WkT, WvT, Qb, Kb, VTb);
  attn_kernel<<<dim3(1024), 256, 0, stream>>>(Qb, Kb, VTb, pad, Ab);
  out_gemm<<<dim3(8, 64), 256, 0, stream>>>(Ab, WoT, (float*)d_out);
}